// Round 7
// baseline (188.606 us; speedup 1.0000x reference)
//
#include <hip/hip_runtime.h>
#include <cstddef>
#include <cstdint>

constexpr int NPTS   = 524288;
constexpr int NG     = 16;
constexpr int GR     = 64;
constexpr int GR3    = GR * GR * GR;   // 262144
constexpr int NNODES = 64;
constexpr int NBINS  = 32768;          // 32^3 spatial cells, morton order

// workspace layout (bytes)
constexpr size_t GRIDS_BYTES = (size_t)NG * GR3 * 8;        // 32 MB: x-pair replicated bf16x2 (uint2/node)
constexpr size_t WS_SORT     = GRIDS_BYTES;
constexpr size_t SORT_BYTES  = (size_t)NPTS * 16;           // 8 MB float4
constexpr size_t WS_KEYR     = WS_SORT + SORT_BYTES;
constexpr size_t KEYR_BYTES  = (size_t)NPTS * 4;            // 2 MB key|rank
constexpr size_t WS_BINS     = WS_KEYR + KEYR_BYTES;
constexpr size_t BINS_BYTES  = (size_t)NBINS * 4;
constexpr size_t WS_MATS     = WS_BINS + BINS_BYTES;
constexpr size_t MATS_BYTES  = 1024;                        // 16*12 floats, padded
constexpr size_t WS_WPACK    = WS_MATS + MATS_BYTES;
constexpr size_t WPACK_BYTES = (size_t)(256 + 512) * 16;    // B0: 256 uint4, B1: 512 uint4
constexpr size_t WS_PART     = WS_WPACK + WPACK_BYTES;
constexpr size_t PART_BYTES  = 128 * 4;                     // scan block partials
constexpr size_t WS_TOTAL    = WS_PART + PART_BYTES;

// prep kernel block-role ranges
constexpr int PREP_REPACK = 4096;      // 4096 blocks * 256 thr * 4 nodes = NG*GR3
constexpr int PREP_HIST   = 2048;      // 2048 blocks * 256 thr = NPTS

typedef _Float16 half8 __attribute__((ext_vector_type(8)));
typedef float    floatx4 __attribute__((ext_vector_type(4)));

__device__ __forceinline__ unsigned part1by2(unsigned x) {
    x &= 0x3ff;
    x = (x | (x << 16)) & 0x030000FF;
    x = (x | (x <<  8)) & 0x0300F00F;
    x = (x | (x <<  4)) & 0x030C30C3;
    x = (x | (x <<  2)) & 0x09249249;
    return x;
}

__device__ __forceinline__ unsigned cell_of(float px, float py, float pz) {
    int cx = (int)((px + 1.0f) * 16.0f); cx = min(max(cx, 0), 31);
    int cy = (int)((py + 1.0f) * 16.0f); cy = min(max(cy, 0), 31);
    int cz = (int)((pz + 1.0f) * 16.0f); cz = min(max(cz, 0), 31);
    return part1by2((unsigned)cx) | (part1by2((unsigned)cy) << 1) | (part1by2((unsigned)cz) << 2);
}

__device__ __forceinline__ unsigned f32_to_bf16_rne(float f) {
    unsigned u = __float_as_uint(f);
    return (u + 0x7fffu + ((u >> 16) & 1u)) >> 16;
}

// pack two floats to fp16x2 (RNE)
__device__ __forceinline__ unsigned pack_h2(float a, float b) {
    unsigned short ua = __builtin_bit_cast(unsigned short, (_Float16)a);
    unsigned short ub = __builtin_bit_cast(unsigned short, (_Float16)b);
    return (unsigned)ua | ((unsigned)ub << 16);
}

__device__ __forceinline__ unsigned short f32_to_h16(float a) {
    return __builtin_bit_cast(unsigned short, (_Float16)a);
}

// ---- fused prep: repack grids | hist | mats | pack weights (independent) ----
__global__ __launch_bounds__(256) void prep_kernel(
    const float* __restrict__ grids, uint2* __restrict__ gout,
    const float* __restrict__ xs, unsigned* __restrict__ bins,
    unsigned* __restrict__ keyrank,
    const float* __restrict__ rot, const float* __restrict__ scl,
    const float* __restrict__ trn, float* __restrict__ mats,
    const float* __restrict__ W0, const float* __restrict__ W1,
    uint4* __restrict__ wpack)
{
    const int bid = blockIdx.x;
    const int tid = threadIdx.x;

    if (bid < PREP_REPACK) {
        // grid repack, 4 consecutive-x nodes per thread (float4 reads)
        const int base = (bid * 256 + tid) * 4;      // global node id, multiple of 4
        const int g    = base >> 18;                 // GR3 = 2^18
        const int node = base & (GR3 - 1);
        const int x    = node & 63;
        const float* p0 = grids + (size_t)g * 2 * GR3 + node;
        const float* p1 = p0 + GR3;
        const float4 c0 = *(const float4*)p0;
        const float4 c1 = *(const float4*)p1;
        // neighbor of element x+3 lives in the NEXT lane's c0.x / c1.x:
        // grab via shfl, only lane 63 (wave boundary) falls back to a load.
        const float s0n = __shfl_down(c0.x, 1, 64);
        const float s1n = __shfl_down(c1.x, 1, 64);
        float d0n, d1n;
        if (x == 60)                 { d0n = c0.w;  d1n = c1.w;  }  // x+3==63: clamp
        else if ((tid & 63) == 63)   { d0n = p0[4]; d1n = p1[4]; }
        else                         { d0n = s0n;   d1n = s1n;   }
        const float e0[5] = {c0.x, c0.y, c0.z, c0.w, d0n};
        const float e1[5] = {c1.x, c1.y, c1.z, c1.w, d1n};
        unsigned pk[5];
        #pragma unroll
        for (int i = 0; i < 5; ++i)
            pk[i] = f32_to_bf16_rne(e0[i]) | (f32_to_bf16_rne(e1[i]) << 16);
        uint4* dst = (uint4*)(gout + (size_t)g * GR3 + node);
        dst[0] = make_uint4(pk[0], pk[1], pk[1], pk[2]);
        dst[1] = make_uint4(pk[2], pk[3], pk[3], pk[4]);
    } else if (bid < PREP_REPACK + PREP_HIST) {
        // histogram + (key, rank) per point
        const int n = (bid - PREP_REPACK) * 256 + tid;
        const unsigned key = cell_of(xs[n*3+0], xs[n*3+1], xs[n*3+2]);
        const unsigned rank = atomicAdd(&bins[key], 1u);
        keyrank[n] = key | (rank << 15);
    } else if (bid == PREP_REPACK + PREP_HIST) {
        // transform matrices
        const int g = tid;
        if (g < NG) {
            float qx = rot[g*4+0], qy = rot[g*4+1], qz = rot[g*4+2], qw = rot[g*4+3];
            const float inv = 1.0f / sqrtf(qx*qx + qy*qy + qz*qz + qw*qw);
            qx *= inv; qy *= inv; qz *= inv; qw *= inv;
            const float sx = expf(scl[g*3+0]);
            const float sy = expf(scl[g*3+1]);
            const float sz = expf(scl[g*3+2]);
            float* m = mats + g * 12;
            m[0] = sx * (1.0f - 2.0f*(qy*qy + qz*qz));
            m[1] = sx * (2.0f*(qx*qy - qz*qw));
            m[2] = sx * (2.0f*(qx*qz + qy*qw));
            m[3] = sy * (2.0f*(qx*qy + qz*qw));
            m[4] = sy * (1.0f - 2.0f*(qx*qx + qz*qz));
            m[5] = sy * (2.0f*(qy*qz - qx*qw));
            m[6] = sz * (2.0f*(qx*qz - qy*qw));
            m[7] = sz * (2.0f*(qy*qz + qx*qw));
            m[8] = sz * (1.0f - 2.0f*(qx*qx + qy*qy));
            m[9]  = trn[g*3+0];
            m[10] = trn[g*3+1];
            m[11] = trn[g*3+2];
        }
    } else {
        // pack W0/W1 into MFMA B-fragment order (fp16).
        // B-frag: lane (c=lane&15, q=lane>>4) holds B[k=q*8+j][n=c], j=0..7.
        const int t = tid >> 6;          // ntile
        const int lane = tid & 63;
        const int q = lane >> 4, c = lane & 15;
        const int n = t * 16 + c;
        {
            unsigned u[4];
            #pragma unroll
            for (int jj = 0; jj < 4; ++jj) {
                const int k0 = q * 8 + 2 * jj;
                u[jj] = pack_h2(W0[k0 * NNODES + n], W0[(k0 + 1) * NNODES + n]);
            }
            wpack[t * 64 + lane] = make_uint4(u[0], u[1], u[2], u[3]);
        }
        #pragma unroll
        for (int ks = 0; ks < 2; ++ks) {
            unsigned u[4];
            #pragma unroll
            for (int jj = 0; jj < 4; ++jj) {
                const int k0 = ks * 32 + q * 8 + 2 * jj;
                u[jj] = pack_h2(W1[k0 * NNODES + n], W1[(k0 + 1) * NNODES + n]);
            }
            wpack[256 + (ks * 4 + t) * 64 + lane] = make_uint4(u[0], u[1], u[2], u[3]);
        }
    }
}

// ---- scanA: per-block exclusive scan of 256 bins + block partial ----
__global__ __launch_bounds__(256) void scanA_kernel(unsigned* __restrict__ bins,
                                                    unsigned* __restrict__ part) {
    __shared__ unsigned s[256];
    const int t = threadIdx.x;
    const int base = blockIdx.x * 256;
    const unsigned v = bins[base + t];
    s[t] = v;
    __syncthreads();
    for (int off = 1; off < 256; off <<= 1) {
        unsigned u = (t >= off) ? s[t - off] : 0u;
        __syncthreads();
        s[t] += u;
        __syncthreads();
    }
    bins[base + t] = s[t] - v;             // within-block exclusive
    if (t == 255) part[blockIdx.x] = s[255];
}

// ---- scatter: scanB folded in (each block wave-scans the 128 partials) ----
__global__ __launch_bounds__(256) void scatter_kernel(const float* __restrict__ xs,
                                                      const unsigned* __restrict__ bins,
                                                      const unsigned* __restrict__ part,
                                                      const unsigned* __restrict__ keyrank,
                                                      float4* __restrict__ sorted) {
    __shared__ unsigned sp[128];           // exclusive scan of the 128 partials
    const int t = threadIdx.x;
    if (t < 64) {
        const unsigned a = part[2 * t];
        const unsigned b = part[2 * t + 1];
        unsigned s = a + b;
        #pragma unroll
        for (int off = 1; off < 64; off <<= 1) {
            const unsigned u = __shfl_up(s, off, 64);
            if (t >= off) s += u;
        }
        const unsigned excl = s - (a + b);
        sp[2 * t]     = excl;
        sp[2 * t + 1] = excl + a;
    }
    __syncthreads();
    const int n = blockIdx.x * 256 + t;
    const unsigned kr = keyrank[n];
    const unsigned key = kr & 0x7fffu;
    const unsigned rank = kr >> 15;
    const unsigned pos = sp[key >> 8] + bins[key] + rank;
    sorted[pos] = make_float4(xs[n*3+0], xs[n*3+1], xs[n*3+2], __int_as_float(n));
}

// ---- per-grid gather geometry ----
struct Geom {
    int i00, i01, i10, i11;
    float ax0, ax1, ay0, ay1, az0, az1;
    unsigned selhi, sello;
};

__device__ __forceinline__ Geom make_geom(const float* __restrict__ m,
                                          float px, float py, float pz, int g) {
    Geom G;
    const float tx = fmaf(m[0], px, fmaf(m[1], py, fmaf(m[2], pz, m[9])));
    const float ty = fmaf(m[3], px, fmaf(m[4], py, fmaf(m[5], pz, m[10])));
    const float tz = fmaf(m[6], px, fmaf(m[7], py, fmaf(m[8], pz, m[11])));
    const float fx = (tx + 1.0f) * 31.5f;
    const float fy = (ty + 1.0f) * 31.5f;
    const float fz = (tz + 1.0f) * 31.5f;
    const float x0f = floorf(fx), y0f = floorf(fy), z0f = floorf(fz);
    const float wx = fx - x0f, wy = fy - y0f, wz = fz - z0f;
    const int x0 = (int)x0f, y0 = (int)y0f, z0 = (int)z0f;
    G.ax0 = ((unsigned)x0       < 64u) ? (1.0f - wx) : 0.0f;
    G.ax1 = ((unsigned)(x0 + 1) < 64u) ? wx          : 0.0f;
    G.ay0 = ((unsigned)y0       < 64u) ? (1.0f - wy) : 0.0f;
    G.ay1 = ((unsigned)(y0 + 1) < 64u) ? wy          : 0.0f;
    G.az0 = ((unsigned)z0       < 64u) ? (1.0f - wz) : 0.0f;
    G.az1 = ((unsigned)(z0 + 1) < 64u) ? wz          : 0.0f;
    G.selhi = (x0 >= 63) ? 1u : 0u;
    G.sello = (x0 <= -1) ? 1u : 0u;
    const int xb  = min(max(x0, 0), 62);
    const int yc0 = min(max(y0, 0), 63),     yc1 = min(max(y0 + 1, 0), 63);
    const int zc0 = min(max(z0, 0), 63),     zc1 = min(max(z0 + 1, 0), 63);
    const int b = (g << 18) + xb;
    G.i00 = b + (zc0 << 12) + (yc0 << 6);
    G.i01 = b + (zc0 << 12) + (yc1 << 6);
    G.i10 = b + (zc1 << 12) + (yc0 << 6);
    G.i11 = b + (zc1 << 12) + (yc1 << 6);
    return G;
}

__device__ __forceinline__ void acc_pair(float& f0, float& f1, const Geom& G,
                                         uint2 q, float wyz) {
    const unsigned v0 = G.selhi ? q.y : q.x;
    const unsigned v1 = G.sello ? q.x : q.y;
    float s0 = G.ax0 * __uint_as_float(v0 << 16);
    s0 = fmaf(G.ax1, __uint_as_float(v1 << 16), s0);
    f0 = fmaf(wyz, s0, f0);
    float s1 = G.ax0 * __uint_as_float(v0 & 0xffff0000u);
    s1 = fmaf(G.ax1, __uint_as_float(v1 & 0xffff0000u), s1);
    f1 = fmaf(wyz, s1, f1);
}

// ---- main fused kernel: gather (VALU, depth-3 named-var prefetch) + MFMA MLP
// XCD-chunked block swizzle: contiguous morton range per XCD -> private 4MB L2
// holds ~1/8 of the 32MB packed grids (FETCH 101->27MB, R1).
// NAMED scalars only (R1: array pipelines get collapsed). Depth-3 (R7): extends
// issue->consume distance ~240->~360cy to cover the ~10% L2-miss tail; +20 VGPR.
// __syncthreads kept (R6: wave-local fences + setprio = +14us pure stall; the
// hardware barrier's phase-alignment is load-bearing).
// LDS 32768B (h0 XOR-swizzled HSTR=64, yf folded into arena).
// launch_bounds (256,4): R2 lesson -- min 5 waves/EU forced VGPR 48 + spill.
// R5 lesson: fdot2/cvt_pkrtz triggered ~270MB/iter scratch at VGPR_Count 64 --
// WRITE_SIZE blowup + cold-dispatch outlier is the spill tell, not VGPR_Count.
constexpr int ARENA_H = 64 * 64;       // ushorts per wave arena (4096 = 8KB)
constexpr int FSTRIDE = 40;            // feats row stride in halves
constexpr int MAIN_NB = NPTS / 256;    // 2048 blocks

__global__ __launch_bounds__(256, 4) void amgsrn_main(
    const float4* __restrict__ sorted,
    const uint2*  __restrict__ gridsP,
    const float*  __restrict__ mats,
    const uint4*  __restrict__ wpack,
    const float*  __restrict__ b0,
    const float*  __restrict__ b1,
    const float*  __restrict__ W2,
    const float*  __restrict__ b2,
    float* __restrict__ out)
{
    __shared__ unsigned short sh[4 * ARENA_H];   // 32768 B total

    const int tid  = threadIdx.x;
    const int lane = tid & 63;
    const int wv   = tid >> 6;
    const int c    = lane & 15;
    const int q    = lane >> 4;
    unsigned short* wa = sh + wv * ARENA_H;

    const int bid = blockIdx.x;
    const int swz = (bid & 7) * (MAIN_NB / 8) + (bid >> 3);   // XCD-chunked
    const int n = swz * 256 + tid;                 // NPTS % 256 == 0: always valid
    const float4 p = sorted[n];
    const float px = p.x, py = p.y, pz = p.z;
    const int orig = __float_as_int(p.w);

    // ---- gather: 16 grids, depth-3 software pipeline (named scalars)
    unsigned pk[NG];
    Geom Ga = make_geom(mats, px, py, pz, 0);
    uint2 a00 = gridsP[Ga.i00], a01 = gridsP[Ga.i01];
    uint2 a10 = gridsP[Ga.i10], a11 = gridsP[Ga.i11];
    Geom Gb = make_geom(mats + 12, px, py, pz, 1);
    uint2 b00 = gridsP[Gb.i00], b01 = gridsP[Gb.i01];
    uint2 b10 = gridsP[Gb.i10], b11 = gridsP[Gb.i11];
    Geom Gc = make_geom(mats + 24, px, py, pz, 2);
    uint2 c00 = gridsP[Gc.i00], c01 = gridsP[Gc.i01];
    uint2 c10 = gridsP[Gc.i10], c11 = gridsP[Gc.i11];
    #pragma unroll
    for (int g = 0; g < NG; ++g) {
        Geom Gn;
        uint2 n00, n01, n10, n11;
        if (g + 3 < NG) {
            Gn = make_geom(mats + (g + 3) * 12, px, py, pz, g + 3);
            n00 = gridsP[Gn.i00]; n01 = gridsP[Gn.i01];
            n10 = gridsP[Gn.i10]; n11 = gridsP[Gn.i11];
        }
        float f0 = 0.0f, f1 = 0.0f;
        acc_pair(f0, f1, Ga, a00, Ga.az0 * Ga.ay0);
        acc_pair(f0, f1, Ga, a01, Ga.az0 * Ga.ay1);
        acc_pair(f0, f1, Ga, a10, Ga.az1 * Ga.ay0);
        acc_pair(f0, f1, Ga, a11, Ga.az1 * Ga.ay1);
        pk[g] = pack_h2(f0, f1);                   // feat 2g (low), 2g+1 (high)
        Ga = Gb; a00 = b00; a01 = b01; a10 = b10; a11 = b11;
        Gb = Gc; b00 = c00; b01 = c01; b10 = c10; b11 = c11;
        if (g + 3 < NG) {
            Gc = Gn; c00 = n00; c01 = n01; c10 = n10; c11 = n11;
        }
    }

    // ---- stage feats to LDS [pt][32 halves], row stride FSTRIDE halves
    {
        uint4* dst = (uint4*)(wa + lane * FSTRIDE); // 80B-aligned -> 16B-aligned
        dst[0] = make_uint4(pk[0],  pk[1],  pk[2],  pk[3]);
        dst[1] = make_uint4(pk[4],  pk[5],  pk[6],  pk[7]);
        dst[2] = make_uint4(pk[8],  pk[9],  pk[10], pk[11]);
        dst[3] = make_uint4(pk[12], pk[13], pk[14], pk[15]);
    }
    __syncthreads();   // fence: feats writes (uint4) -> A0 reads (half8)

    // ---- A0 fragments: A[m=pt][k=feat], lane holds pt=m*16+c, k=q*8..q*8+7
    half8 a0[4];
    #pragma unroll
    for (int m = 0; m < 4; ++m)
        a0[m] = *(const half8*)(wa + (m * 16 + c) * FSTRIDE + q * 8);

    // ---- B fragments + bias/W2 lane constants
    half8 b0f[4], b1f[2][4];
    #pragma unroll
    for (int t = 0; t < 4; ++t)
        b0f[t] = __builtin_bit_cast(half8, wpack[t * 64 + lane]);
    #pragma unroll
    for (int ks = 0; ks < 2; ++ks)
        #pragma unroll
        for (int t = 0; t < 4; ++t)
            b1f[ks][t] = __builtin_bit_cast(half8, wpack[256 + (ks * 4 + t) * 64 + lane]);
    float b0v[4], b1v[4], w2v[4];
    #pragma unroll
    for (int t = 0; t < 4; ++t) {
        b0v[t] = b0[t * 16 + c];
        b1v[t] = b1[t * 16 + c];
        w2v[t] = W2[t * 16 + c];
    }
    const float b2s = b2[0];

    __syncthreads();   // fence: A0 reads complete before layer-0 stores reuse the arena

    // ---- layer 0: 16 MFMA; D gives lane col=node(c+t*16), rows=pt(m*16+q*4+r)
    // store relu(h0) as fp16 to LDS [pt][node], HSTR=64 with 16B-granule XOR
    // swizzle: half-idx = row*64 + ((node>>3 ^ (row&7))<<3) + (node&7)
    #pragma unroll
    for (int t = 0; t < 4; ++t) {
        #pragma unroll
        for (int m = 0; m < 4; ++m) {
            floatx4 acc = {b0v[t], b0v[t], b0v[t], b0v[t]};
            acc = __builtin_amdgcn_mfma_f32_16x16x32_f16(a0[m], b0f[t], acc, 0, 0, 0);
            const int gnode = 2 * t + (c >> 3);    // node>>3
            const int nlow  = c & 7;               // node&7
            const int ptb   = m * 16 + q * 4;
            #pragma unroll
            for (int r = 0; r < 4; ++r) {
                const int row = ptb + r;
                wa[(row << 6) + ((gnode ^ (row & 7)) << 3) + nlow] =
                    f32_to_h16(fmaxf(acc[r], 0.0f));
            }
        }
    }
    __syncthreads();   // fence: h0 writes (ushort) -> A1 reads (half8)

    // ---- A1 fragments: A[m=pt][k=node], 16B reads at swizzled granules
    half8 a1[4][2];
    #pragma unroll
    for (int m = 0; m < 4; ++m) {
        const int row = m * 16 + c;
        #pragma unroll
        for (int ks = 0; ks < 2; ++ks)
            a1[m][ks] = *(const half8*)(wa + (row << 6) + (((ks * 4 + q) ^ (c & 7)) << 3));
    }

    // ---- layer 1 (32 MFMA) + layer 2 folded into epilogue on D-registers
    float p4[4][4];
    #pragma unroll
    for (int m = 0; m < 4; ++m)
        #pragma unroll
        for (int r = 0; r < 4; ++r) p4[m][r] = 0.0f;

    #pragma unroll
    for (int t = 0; t < 4; ++t) {
        #pragma unroll
        for (int m = 0; m < 4; ++m) {
            floatx4 acc = {b1v[t], b1v[t], b1v[t], b1v[t]};
            acc = __builtin_amdgcn_mfma_f32_16x16x32_f16(a1[m][0], b1f[0][t], acc, 0, 0, 0);
            acc = __builtin_amdgcn_mfma_f32_16x16x32_f16(a1[m][1], b1f[1][t], acc, 0, 0, 0);
            #pragma unroll
            for (int r = 0; r < 4; ++r)
                p4[m][r] = fmaf(fmaxf(acc[r], 0.0f), w2v[t], p4[m][r]);
        }
    }

    // reduce partials across the 16 cols (lanes differing in low 4 bits)
    #pragma unroll
    for (int m = 0; m < 4; ++m)
        #pragma unroll
        for (int r = 0; r < 4; ++r) {
            float v = p4[m][r];
            v += __shfl_xor(v, 1, 64);
            v += __shfl_xor(v, 2, 64);
            v += __shfl_xor(v, 4, 64);
            v += __shfl_xor(v, 8, 64);
            p4[m][r] = v + b2s;
        }

    // lane c==0 of each quad publishes its 16 point results into the arena
    // (h0 region is dead after the A1 reads; MFMA data-deps drained them)
    float* yf = (float*)wa;
    if (c == 0) {
        #pragma unroll
        for (int m = 0; m < 4; ++m)
            #pragma unroll
            for (int r = 0; r < 4; ++r)
                yf[m * 16 + q * 4 + r] = p4[m][r];
    }
    __syncthreads();   // fence: yf writes -> yf reads
    out[orig] = yf[lane];
}

// ---- fallback (unsorted, original layout, pure fp32) used if ws too small ----
__global__ __launch_bounds__(256, 3) void amgsrn_fused_fallback(
    const float* __restrict__ xs,
    const float* __restrict__ rot,
    const float* __restrict__ scl,
    const float* __restrict__ trn,
    const float* __restrict__ grids,
    const float* __restrict__ W0,
    const float* __restrict__ b0,
    const float* __restrict__ W1,
    const float* __restrict__ b1,
    const float* __restrict__ W2,
    const float* __restrict__ b2,
    float* __restrict__ out)
{
    __shared__ float sM[NG][12];
    const int tid = threadIdx.x;
    if (tid < NG) {
        const int g = tid;
        float qx = rot[g*4+0], qy = rot[g*4+1], qz = rot[g*4+2], qw = rot[g*4+3];
        const float inv = 1.0f / sqrtf(qx*qx + qy*qy + qz*qz + qw*qw);
        qx *= inv; qy *= inv; qz *= inv; qw *= inv;
        const float sx = expf(scl[g*3+0]);
        const float sy = expf(scl[g*3+1]);
        const float sz = expf(scl[g*3+2]);
        sM[g][0] = sx * (1.0f - 2.0f*(qy*qy + qz*qz));
        sM[g][1] = sx * (2.0f*(qx*qy - qz*qw));
        sM[g][2] = sx * (2.0f*(qx*qz + qy*qw));
        sM[g][3] = sy * (2.0f*(qx*qy + qz*qw));
        sM[g][4] = sy * (1.0f - 2.0f*(qx*qx + qz*qz));
        sM[g][5] = sy * (2.0f*(qy*qz - qx*qw));
        sM[g][6] = sz * (2.0f*(qx*qz - qy*qw));
        sM[g][7] = sz * (2.0f*(qy*qz + qx*qw));
        sM[g][8] = sz * (1.0f - 2.0f*(qx*qx + qy*qy));
        sM[g][9]  = trn[g*3+0];
        sM[g][10] = trn[g*3+1];
        sM[g][11] = trn[g*3+2];
    }
    __syncthreads();

    const int n = blockIdx.x * blockDim.x + tid;
    if (n >= NPTS) return;
    const float px = xs[n*3+0];
    const float py = xs[n*3+1];
    const float pz = xs[n*3+2];

    float h0[NNODES];
    #pragma unroll
    for (int j = 0; j < NNODES; ++j) h0[j] = b0[j];

    #pragma unroll
    for (int g = 0; g < NG; ++g) {
        const float* m = sM[g];
        const float tx = m[0]*px + m[1]*py + m[2]*pz + m[9];
        const float ty = m[3]*px + m[4]*py + m[5]*pz + m[10];
        const float tz = m[6]*px + m[7]*py + m[8]*pz + m[11];
        const float fx = (tx + 1.0f) * 31.5f;
        const float fy = (ty + 1.0f) * 31.5f;
        const float fz = (tz + 1.0f) * 31.5f;
        const float x0f = floorf(fx), y0f = floorf(fy), z0f = floorf(fz);
        const float wx = fx - x0f, wy = fy - y0f, wz = fz - z0f;
        const int x0 = (int)x0f, y0 = (int)y0f, z0 = (int)z0f;
        const float* gb = grids + (size_t)g * (size_t)(2 * GR3);
        float f0 = 0.0f, f1 = 0.0f;
        #pragma unroll
        for (int dz = 0; dz < 2; ++dz) {
            #pragma unroll
            for (int dy = 0; dy < 2; ++dy) {
                #pragma unroll
                for (int dx = 0; dx < 2; ++dx) {
                    const int xi = x0 + dx, yi = y0 + dy, zi = z0 + dz;
                    const bool valid = ((unsigned)xi < (unsigned)GR) &
                                       ((unsigned)yi < (unsigned)GR) &
                                       ((unsigned)zi < (unsigned)GR);
                    const int xc = min(max(xi, 0), GR-1);
                    const int yc = min(max(yi, 0), GR-1);
                    const int zc = min(max(zi, 0), GR-1);
                    float w = (dx ? wx : 1.0f - wx) *
                              (dy ? wy : 1.0f - wy) *
                              (dz ? wz : 1.0f - wz);
                    w = valid ? w : 0.0f;
                    const int idx = (zc * GR + yc) * GR + xc;
                    f0 = fmaf(w, gb[idx], f0);
                    f1 = fmaf(w, gb[idx + GR3], f1);
                }
            }
        }
        const float* w0a = W0 + (2*g    ) * NNODES;
        const float* w0b = W0 + (2*g + 1) * NNODES;
        #pragma unroll
        for (int j = 0; j < NNODES; ++j)
            h0[j] = fmaf(f1, w0b[j], fmaf(f0, w0a[j], h0[j]));
    }
    #pragma unroll
    for (int j = 0; j < NNODES; ++j) h0[j] = fmaxf(h0[j], 0.0f);

    float y = b2[0];
    #pragma unroll
    for (int half = 0; half < 2; ++half) {
        float h1[32];
        #pragma unroll
        for (int j = 0; j < 32; ++j) h1[j] = b1[half * 32 + j];
        #pragma unroll
        for (int k = 0; k < NNODES; ++k) {
            const float a = h0[k];
            const float* w = W1 + k * NNODES + half * 32;
            #pragma unroll
            for (int j = 0; j < 32; ++j) h1[j] = fmaf(a, w[j], h1[j]);
        }
        #pragma unroll
        for (int j = 0; j < 32; ++j) y = fmaf(fmaxf(h1[j], 0.0f), W2[half * 32 + j], y);
    }

    out[n] = y;
}

extern "C" void kernel_launch(void* const* d_in, const int* in_sizes, int n_in,
                              void* d_out, int out_size, void* d_ws, size_t ws_size,
                              hipStream_t stream) {
    const float* xs  = (const float*)d_in[0];
    const float* rot = (const float*)d_in[1];
    const float* scl = (const float*)d_in[2];
    const float* trn = (const float*)d_in[3];
    const float* gr  = (const float*)d_in[4];
    const float* W0  = (const float*)d_in[5];
    const float* b0  = (const float*)d_in[6];
    const float* W1  = (const float*)d_in[7];
    const float* b1  = (const float*)d_in[8];
    const float* W2  = (const float*)d_in[9];
    const float* b2  = (const float*)d_in[10];
    float* out = (float*)d_out;

    if (ws_size < WS_TOTAL) {
        dim3 grid((NPTS + 255) / 256), block(256);
        hipLaunchKernelGGL(amgsrn_fused_fallback, grid, block, 0, stream,
                           xs, rot, scl, trn, gr, W0, b0, W1, b1, W2, b2, out);
        return;
    }

    char* ws = (char*)d_ws;
    uint2*    gridsP  = (uint2*)(ws);
    float4*   sorted  = (float4*)(ws + WS_SORT);
    unsigned* keyrank = (unsigned*)(ws + WS_KEYR);
    unsigned* bins    = (unsigned*)(ws + WS_BINS);
    float*    mats    = (float*)(ws + WS_MATS);
    uint4*    wpack   = (uint4*)(ws + WS_WPACK);
    unsigned* part    = (unsigned*)(ws + WS_PART);

    (void)hipMemsetAsync(bins, 0, BINS_BYTES, stream);
    hipLaunchKernelGGL(prep_kernel, dim3(PREP_REPACK + PREP_HIST + 2), dim3(256), 0, stream,
                       gr, gridsP, xs, bins, keyrank,
                       rot, scl, trn, mats, W0, W1, wpack);
    hipLaunchKernelGGL(scanA_kernel, dim3(NBINS / 256), dim3(256), 0, stream, bins, part);
    hipLaunchKernelGGL(scatter_kernel, dim3(NPTS / 256), dim3(256), 0, stream,
                       xs, bins, part, keyrank, sorted);
    hipLaunchKernelGGL(amgsrn_main, dim3(NPTS / 256), dim3(256), 0, stream,
                       sorted, gridsP, mats, wpack, b0, b1, W2, b2, out);
}

// Round 8
// 174.125 us; speedup vs baseline: 1.0832x; 1.0832x over previous
//
#include <hip/hip_runtime.h>
#include <cstddef>
#include <cstdint>

constexpr int NPTS   = 524288;
constexpr int NG     = 16;
constexpr int GR     = 64;
constexpr int GR3    = GR * GR * GR;   // 262144
constexpr int NNODES = 64;
constexpr int NBINS  = 32768;          // 32^3 spatial cells, morton order

// workspace layout (bytes)
constexpr size_t GRIDS_BYTES = (size_t)NG * GR3 * 8;        // 32 MB: y-pair bf16x2 (uint2/node)
constexpr size_t WS_SORT     = GRIDS_BYTES;
constexpr size_t SORT_BYTES  = (size_t)NPTS * 16;           // 8 MB float4
constexpr size_t WS_KEYR     = WS_SORT + SORT_BYTES;
constexpr size_t KEYR_BYTES  = (size_t)NPTS * 4;            // 2 MB key|rank
constexpr size_t WS_BINS     = WS_KEYR + KEYR_BYTES;
constexpr size_t BINS_BYTES  = (size_t)NBINS * 4;
constexpr size_t WS_MATS     = WS_BINS + BINS_BYTES;
constexpr size_t MATS_BYTES  = 1024;                        // 16*12 floats, padded
constexpr size_t WS_WPACK    = WS_MATS + MATS_BYTES;
constexpr size_t WPACK_BYTES = (size_t)(256 + 512) * 16;    // B0: 256 uint4, B1: 512 uint4
constexpr size_t WS_PART     = WS_WPACK + WPACK_BYTES;
constexpr size_t PART_BYTES  = 128 * 4;                     // scan block partials
constexpr size_t WS_TOTAL    = WS_PART + PART_BYTES;

// prep kernel block-role ranges
constexpr int PREP_REPACK = 4096;      // 4096 blocks * 256 thr * 4 nodes = NG*GR3
constexpr int PREP_HIST   = 2048;      // 2048 blocks * 256 thr = NPTS

typedef _Float16 half8 __attribute__((ext_vector_type(8)));
typedef float    floatx4 __attribute__((ext_vector_type(4)));

__device__ __forceinline__ unsigned part1by2(unsigned x) {
    x &= 0x3ff;
    x = (x | (x << 16)) & 0x030000FF;
    x = (x | (x <<  8)) & 0x0300F00F;
    x = (x | (x <<  4)) & 0x030C30C3;
    x = (x | (x <<  2)) & 0x09249249;
    return x;
}

__device__ __forceinline__ unsigned cell_of(float px, float py, float pz) {
    int cx = (int)((px + 1.0f) * 16.0f); cx = min(max(cx, 0), 31);
    int cy = (int)((py + 1.0f) * 16.0f); cy = min(max(cy, 0), 31);
    int cz = (int)((pz + 1.0f) * 16.0f); cz = min(max(cz, 0), 31);
    return part1by2((unsigned)cx) | (part1by2((unsigned)cy) << 1) | (part1by2((unsigned)cz) << 2);
}

__device__ __forceinline__ unsigned f32_to_bf16_rne(float f) {
    unsigned u = __float_as_uint(f);
    return (u + 0x7fffu + ((u >> 16) & 1u)) >> 16;
}

// pack two floats into one u32: bf16(a) low | bf16(b) high
__device__ __forceinline__ unsigned pack_bf2(float a, float b) {
    return f32_to_bf16_rne(a) | (f32_to_bf16_rne(b) << 16);
}

// pack two floats to fp16x2 (RNE)
__device__ __forceinline__ unsigned pack_h2(float a, float b) {
    unsigned short ua = __builtin_bit_cast(unsigned short, (_Float16)a);
    unsigned short ub = __builtin_bit_cast(unsigned short, (_Float16)b);
    return (unsigned)ua | ((unsigned)ub << 16);
}

__device__ __forceinline__ unsigned short f32_to_h16(float a) {
    return __builtin_bit_cast(unsigned short, (_Float16)a);
}

// 16B load at 8B-aligned address: memcpy is correct-by-construction
// (emits global_load_dwordx4 when unaligned-x4 is legal, else 2x dwordx2).
__device__ __forceinline__ uint4 load16_a8(const uint2* p) {
    uint4 v;
    __builtin_memcpy(&v, p, 16);
    return v;
}

// ---- fused prep: repack grids | hist | mats | pack weights (independent) ----
// grid repack layout (R8, y-pair): node(g,z,y,x) uint2 =
//   { bf16x2(f0,f1)@(x,y,z), bf16x2(f0,f1)@(x,min(y+1,63),z) }
// A single 16B load at (z,yb,xb) then covers nodes xb and xb+1 -> all four
// (x,y) taps of a trilinear corner -> 2 loads/grid instead of 4.
__global__ __launch_bounds__(256) void prep_kernel(
    const float* __restrict__ grids, uint2* __restrict__ gout,
    const float* __restrict__ xs, unsigned* __restrict__ bins,
    unsigned* __restrict__ keyrank,
    const float* __restrict__ rot, const float* __restrict__ scl,
    const float* __restrict__ trn, float* __restrict__ mats,
    const float* __restrict__ W0, const float* __restrict__ W1,
    uint4* __restrict__ wpack)
{
    const int bid = blockIdx.x;
    const int tid = threadIdx.x;

    if (bid < PREP_REPACK) {
        // grid repack, 4 consecutive-x nodes per thread (float4 reads).
        // Needs rows y and y+1 (clamped); the y+1 row re-read is L2-absorbed
        // (adjacent blocks touch it as their own row at ~the same time).
        const int base = (bid * 256 + tid) * 4;      // global node id, multiple of 4
        const int g    = base >> 18;                 // GR3 = 2^18
        const int node = base & (GR3 - 1);
        const int y    = (node >> 6) & 63;
        const int ystep = (y == 63) ? 0 : 64;        // y+1 clamp
        const float* p0 = grids + (size_t)g * 2 * GR3 + node;   // f0 @ (z,y,x..x+3)
        const float* p1 = p0 + GR3;                              // f1
        const float4 a0 = *(const float4*)p0;              // f0 @ y
        const float4 b0 = *(const float4*)(p0 + ystep);    // f0 @ y+1
        const float4 a1 = *(const float4*)p1;              // f1 @ y
        const float4 b1 = *(const float4*)(p1 + ystep);    // f1 @ y+1
        uint4* dst = (uint4*)(gout + (size_t)g * GR3 + node);
        dst[0] = make_uint4(pack_bf2(a0.x, a1.x), pack_bf2(b0.x, b1.x),
                            pack_bf2(a0.y, a1.y), pack_bf2(b0.y, b1.y));
        dst[1] = make_uint4(pack_bf2(a0.z, a1.z), pack_bf2(b0.z, b1.z),
                            pack_bf2(a0.w, a1.w), pack_bf2(b0.w, b1.w));
    } else if (bid < PREP_REPACK + PREP_HIST) {
        // histogram + (key, rank) per point
        const int n = (bid - PREP_REPACK) * 256 + tid;
        const unsigned key = cell_of(xs[n*3+0], xs[n*3+1], xs[n*3+2]);
        const unsigned rank = atomicAdd(&bins[key], 1u);
        keyrank[n] = key | (rank << 15);
    } else if (bid == PREP_REPACK + PREP_HIST) {
        // transform matrices
        const int g = tid;
        if (g < NG) {
            float qx = rot[g*4+0], qy = rot[g*4+1], qz = rot[g*4+2], qw = rot[g*4+3];
            const float inv = 1.0f / sqrtf(qx*qx + qy*qy + qz*qz + qw*qw);
            qx *= inv; qy *= inv; qz *= inv; qw *= inv;
            const float sx = expf(scl[g*3+0]);
            const float sy = expf(scl[g*3+1]);
            const float sz = expf(scl[g*3+2]);
            float* m = mats + g * 12;
            m[0] = sx * (1.0f - 2.0f*(qy*qy + qz*qz));
            m[1] = sx * (2.0f*(qx*qy - qz*qw));
            m[2] = sx * (2.0f*(qx*qz + qy*qw));
            m[3] = sy * (2.0f*(qx*qy + qz*qw));
            m[4] = sy * (1.0f - 2.0f*(qx*qx + qz*qz));
            m[5] = sy * (2.0f*(qy*qz - qx*qw));
            m[6] = sz * (2.0f*(qx*qz - qy*qw));
            m[7] = sz * (2.0f*(qy*qz + qx*qw));
            m[8] = sz * (1.0f - 2.0f*(qx*qx + qy*qy));
            m[9]  = trn[g*3+0];
            m[10] = trn[g*3+1];
            m[11] = trn[g*3+2];
        }
    } else {
        // pack W0/W1 into MFMA B-fragment order (fp16).
        // B-frag: lane (c=lane&15, q=lane>>4) holds B[k=q*8+j][n=c], j=0..7.
        const int t = tid >> 6;          // ntile
        const int lane = tid & 63;
        const int q = lane >> 4, c = lane & 15;
        const int n = t * 16 + c;
        {
            unsigned u[4];
            #pragma unroll
            for (int jj = 0; jj < 4; ++jj) {
                const int k0 = q * 8 + 2 * jj;
                u[jj] = pack_h2(W0[k0 * NNODES + n], W0[(k0 + 1) * NNODES + n]);
            }
            wpack[t * 64 + lane] = make_uint4(u[0], u[1], u[2], u[3]);
        }
        #pragma unroll
        for (int ks = 0; ks < 2; ++ks) {
            unsigned u[4];
            #pragma unroll
            for (int jj = 0; jj < 4; ++jj) {
                const int k0 = ks * 32 + q * 8 + 2 * jj;
                u[jj] = pack_h2(W1[k0 * NNODES + n], W1[(k0 + 1) * NNODES + n]);
            }
            wpack[256 + (ks * 4 + t) * 64 + lane] = make_uint4(u[0], u[1], u[2], u[3]);
        }
    }
}

// ---- scanA: per-block exclusive scan of 256 bins + block partial ----
__global__ __launch_bounds__(256) void scanA_kernel(unsigned* __restrict__ bins,
                                                    unsigned* __restrict__ part) {
    __shared__ unsigned s[256];
    const int t = threadIdx.x;
    const int base = blockIdx.x * 256;
    const unsigned v = bins[base + t];
    s[t] = v;
    __syncthreads();
    for (int off = 1; off < 256; off <<= 1) {
        unsigned u = (t >= off) ? s[t - off] : 0u;
        __syncthreads();
        s[t] += u;
        __syncthreads();
    }
    bins[base + t] = s[t] - v;             // within-block exclusive
    if (t == 255) part[blockIdx.x] = s[255];
}

// ---- scatter: scanB folded in (each block wave-scans the 128 partials) ----
__global__ __launch_bounds__(256) void scatter_kernel(const float* __restrict__ xs,
                                                      const unsigned* __restrict__ bins,
                                                      const unsigned* __restrict__ part,
                                                      const unsigned* __restrict__ keyrank,
                                                      float4* __restrict__ sorted) {
    __shared__ unsigned sp[128];           // exclusive scan of the 128 partials
    const int t = threadIdx.x;
    if (t < 64) {
        const unsigned a = part[2 * t];
        const unsigned b = part[2 * t + 1];
        unsigned s = a + b;
        #pragma unroll
        for (int off = 1; off < 64; off <<= 1) {
            const unsigned u = __shfl_up(s, off, 64);
            if (t >= off) s += u;
        }
        const unsigned excl = s - (a + b);
        sp[2 * t]     = excl;
        sp[2 * t + 1] = excl + a;
    }
    __syncthreads();
    const int n = blockIdx.x * 256 + t;
    const unsigned kr = keyrank[n];
    const unsigned key = kr & 0x7fffu;
    const unsigned rank = kr >> 15;
    const unsigned pos = sp[key >> 8] + bins[key] + rank;
    sorted[pos] = make_float4(xs[n*3+0], xs[n*3+1], xs[n*3+2], __int_as_float(n));
}

// ---- per-grid gather geometry (y-pair layout) ----
// iz0/iz1: node index of (zc, yb, xb) for the two z planes; one 16B load there
// spans nodes xb,xb+1 each holding the y-pair {yb, yb+1}.
// Boundary: xb=clamp(x0,0,62), yb=clamp(y0,0,62); selx*/sely* pick the correct
// half/element at the edges (weights already zeroed out-of-range).
struct Geom {
    int iz0, iz1;
    float ax0, ax1, ay0, ay1, az0, az1;
    unsigned selxhi, selxlo, selyhi, selylo;
};

__device__ __forceinline__ Geom make_geom(const float* __restrict__ m,
                                          float px, float py, float pz, int g) {
    Geom G;
    const float tx = fmaf(m[0], px, fmaf(m[1], py, fmaf(m[2], pz, m[9])));
    const float ty = fmaf(m[3], px, fmaf(m[4], py, fmaf(m[5], pz, m[10])));
    const float tz = fmaf(m[6], px, fmaf(m[7], py, fmaf(m[8], pz, m[11])));
    const float fx = (tx + 1.0f) * 31.5f;
    const float fy = (ty + 1.0f) * 31.5f;
    const float fz = (tz + 1.0f) * 31.5f;
    const float x0f = floorf(fx), y0f = floorf(fy), z0f = floorf(fz);
    const float wx = fx - x0f, wy = fy - y0f, wz = fz - z0f;
    const int x0 = (int)x0f, y0 = (int)y0f, z0 = (int)z0f;
    G.ax0 = ((unsigned)x0       < 64u) ? (1.0f - wx) : 0.0f;
    G.ax1 = ((unsigned)(x0 + 1) < 64u) ? wx          : 0.0f;
    G.ay0 = ((unsigned)y0       < 64u) ? (1.0f - wy) : 0.0f;
    G.ay1 = ((unsigned)(y0 + 1) < 64u) ? wy          : 0.0f;
    G.az0 = ((unsigned)z0       < 64u) ? (1.0f - wz) : 0.0f;
    G.az1 = ((unsigned)(z0 + 1) < 64u) ? wz          : 0.0f;
    G.selxhi = (x0 >= 63) ? 1u : 0u;
    G.selxlo = (x0 <= -1) ? 1u : 0u;
    G.selyhi = (y0 >= 63) ? 1u : 0u;
    G.selylo = (y0 <= -1) ? 1u : 0u;
    const int xb  = min(max(x0, 0), 62);
    const int yb  = min(max(y0, 0), 62);
    const int zc0 = min(max(z0, 0), 63), zc1 = min(max(z0 + 1, 0), 63);
    const int b = (g << 18) + (yb << 6) + xb;
    G.iz0 = b + (zc0 << 12);
    G.iz1 = b + (zc1 << 12);
    return G;
}

// one z-plane accumulate: v = {A.y0, A.y1, B.y0, B.y1} (A=node xb, B=node xb+1),
// each u32 = bf16(f0) low | bf16(f1) high. wij = axi*ayj precomputed.
__device__ __forceinline__ void acc_z(float& f0, float& f1, const Geom& G, uint4 v,
                                      float w00, float w01, float w10, float w11,
                                      float az) {
    const unsigned x0l = G.selxhi ? v.z : v.x;   // ax0-tap, y-low
    const unsigned x0h = G.selxhi ? v.w : v.y;   // ax0-tap, y-high
    const unsigned x1l = G.selxlo ? v.x : v.z;   // ax1-tap, y-low
    const unsigned x1h = G.selxlo ? v.y : v.w;   // ax1-tap, y-high
    const unsigned t00 = G.selyhi ? x0h : x0l;   // (ax0, ay0)
    const unsigned t01 = G.selylo ? x0l : x0h;   // (ax0, ay1)
    const unsigned t10 = G.selyhi ? x1h : x1l;   // (ax1, ay0)
    const unsigned t11 = G.selylo ? x1l : x1h;   // (ax1, ay1)
    float s0 = w00 * __uint_as_float(t00 << 16);
    s0 = fmaf(w01, __uint_as_float(t01 << 16), s0);
    s0 = fmaf(w10, __uint_as_float(t10 << 16), s0);
    s0 = fmaf(w11, __uint_as_float(t11 << 16), s0);
    f0 = fmaf(az, s0, f0);
    float s1 = w00 * __uint_as_float(t00 & 0xffff0000u);
    s1 = fmaf(w01, __uint_as_float(t01 & 0xffff0000u), s1);
    s1 = fmaf(w10, __uint_as_float(t10 & 0xffff0000u), s1);
    s1 = fmaf(w11, __uint_as_float(t11 & 0xffff0000u), s1);
    f1 = fmaf(az, s1, f1);
}

// ---- main fused kernel: gather (VALU, depth-2 named-var prefetch) + MFMA MLP
// R8: y-pair layout -> 2 x 16B loads/grid (was 4 x 8B): halves the scattered
// load-instruction count and distinct-line transactions in the L1/TA path --
// the hypothesized residual after R1-R7 eliminated traffic/occupancy/schedule.
// XCD-chunked block swizzle kept (FETCH 101->27MB, R1). Depth-2 NAMED scalars
// (R1: arrays collapse). __syncthreads kept (R6: wave fences +14us stall).
// launch_bounds (256,4) (R2: min=5 forced spill). LDS 32768B.
constexpr int ARENA_H = 64 * 64;       // ushorts per wave arena (4096 = 8KB)
constexpr int FSTRIDE = 40;            // feats row stride in halves
constexpr int MAIN_NB = NPTS / 256;    // 2048 blocks

__global__ __launch_bounds__(256, 4) void amgsrn_main(
    const float4* __restrict__ sorted,
    const uint2*  __restrict__ gridsP,
    const float*  __restrict__ mats,
    const uint4*  __restrict__ wpack,
    const float*  __restrict__ b0,
    const float*  __restrict__ b1,
    const float*  __restrict__ W2,
    const float*  __restrict__ b2,
    float* __restrict__ out)
{
    __shared__ unsigned short sh[4 * ARENA_H];   // 32768 B total

    const int tid  = threadIdx.x;
    const int lane = tid & 63;
    const int wv   = tid >> 6;
    const int c    = lane & 15;
    const int q    = lane >> 4;
    unsigned short* wa = sh + wv * ARENA_H;

    const int bid = blockIdx.x;
    const int swz = (bid & 7) * (MAIN_NB / 8) + (bid >> 3);   // XCD-chunked
    const int n = swz * 256 + tid;                 // NPTS % 256 == 0: always valid
    const float4 p = sorted[n];
    const float px = p.x, py = p.y, pz = p.z;
    const int orig = __float_as_int(p.w);

    // ---- gather: 16 grids, depth-2 software pipeline (named scalars)
    unsigned pk[NG];
    Geom Ga = make_geom(mats, px, py, pz, 0);
    uint4 va0 = load16_a8(gridsP + Ga.iz0);
    uint4 va1 = load16_a8(gridsP + Ga.iz1);
    Geom Gb = make_geom(mats + 12, px, py, pz, 1);
    uint4 vb0 = load16_a8(gridsP + Gb.iz0);
    uint4 vb1 = load16_a8(gridsP + Gb.iz1);
    #pragma unroll
    for (int g = 0; g < NG; ++g) {
        Geom Gn;
        uint4 vn0, vn1;
        if (g + 2 < NG) {
            Gn = make_geom(mats + (g + 2) * 12, px, py, pz, g + 2);
            vn0 = load16_a8(gridsP + Gn.iz0);
            vn1 = load16_a8(gridsP + Gn.iz1);
        }
        const float w00 = Ga.ax0 * Ga.ay0, w01 = Ga.ax0 * Ga.ay1;
        const float w10 = Ga.ax1 * Ga.ay0, w11 = Ga.ax1 * Ga.ay1;
        float f0 = 0.0f, f1 = 0.0f;
        acc_z(f0, f1, Ga, va0, w00, w01, w10, w11, Ga.az0);
        acc_z(f0, f1, Ga, va1, w00, w01, w10, w11, Ga.az1);
        pk[g] = pack_h2(f0, f1);                   // feat 2g (low), 2g+1 (high)
        Ga = Gb; va0 = vb0; va1 = vb1;
        if (g + 2 < NG) {
            Gb = Gn; vb0 = vn0; vb1 = vn1;
        }
    }

    // ---- stage feats to LDS [pt][32 halves], row stride FSTRIDE halves
    {
        uint4* dst = (uint4*)(wa + lane * FSTRIDE); // 80B-aligned -> 16B-aligned
        dst[0] = make_uint4(pk[0],  pk[1],  pk[2],  pk[3]);
        dst[1] = make_uint4(pk[4],  pk[5],  pk[6],  pk[7]);
        dst[2] = make_uint4(pk[8],  pk[9],  pk[10], pk[11]);
        dst[3] = make_uint4(pk[12], pk[13], pk[14], pk[15]);
    }
    __syncthreads();   // fence: feats writes (uint4) -> A0 reads (half8)

    // ---- A0 fragments: A[m=pt][k=feat], lane holds pt=m*16+c, k=q*8..q*8+7
    half8 a0[4];
    #pragma unroll
    for (int m = 0; m < 4; ++m)
        a0[m] = *(const half8*)(wa + (m * 16 + c) * FSTRIDE + q * 8);

    // ---- B fragments + bias/W2 lane constants
    half8 b0f[4], b1f[2][4];
    #pragma unroll
    for (int t = 0; t < 4; ++t)
        b0f[t] = __builtin_bit_cast(half8, wpack[t * 64 + lane]);
    #pragma unroll
    for (int ks = 0; ks < 2; ++ks)
        #pragma unroll
        for (int t = 0; t < 4; ++t)
            b1f[ks][t] = __builtin_bit_cast(half8, wpack[256 + (ks * 4 + t) * 64 + lane]);
    float b0v[4], b1v[4], w2v[4];
    #pragma unroll
    for (int t = 0; t < 4; ++t) {
        b0v[t] = b0[t * 16 + c];
        b1v[t] = b1[t * 16 + c];
        w2v[t] = W2[t * 16 + c];
    }
    const float b2s = b2[0];

    __syncthreads();   // fence: A0 reads complete before layer-0 stores reuse the arena

    // ---- layer 0: 16 MFMA; D gives lane col=node(c+t*16), rows=pt(m*16+q*4+r)
    // store relu(h0) as fp16 to LDS [pt][node], HSTR=64 with 16B-granule XOR
    // swizzle: half-idx = row*64 + ((node>>3 ^ (row&7))<<3) + (node&7)
    #pragma unroll
    for (int t = 0; t < 4; ++t) {
        #pragma unroll
        for (int m = 0; m < 4; ++m) {
            floatx4 acc = {b0v[t], b0v[t], b0v[t], b0v[t]};
            acc = __builtin_amdgcn_mfma_f32_16x16x32_f16(a0[m], b0f[t], acc, 0, 0, 0);
            const int gnode = 2 * t + (c >> 3);    // node>>3
            const int nlow  = c & 7;               // node&7
            const int ptb   = m * 16 + q * 4;
            #pragma unroll
            for (int r = 0; r < 4; ++r) {
                const int row = ptb + r;
                wa[(row << 6) + ((gnode ^ (row & 7)) << 3) + nlow] =
                    f32_to_h16(fmaxf(acc[r], 0.0f));
            }
        }
    }
    __syncthreads();   // fence: h0 writes (ushort) -> A1 reads (half8)

    // ---- A1 fragments: A[m=pt][k=node], 16B reads at swizzled granules
    half8 a1[4][2];
    #pragma unroll
    for (int m = 0; m < 4; ++m) {
        const int row = m * 16 + c;
        #pragma unroll
        for (int ks = 0; ks < 2; ++ks)
            a1[m][ks] = *(const half8*)(wa + (row << 6) + (((ks * 4 + q) ^ (c & 7)) << 3));
    }

    // ---- layer 1 (32 MFMA) + layer 2 folded into epilogue on D-registers
    float p4[4][4];
    #pragma unroll
    for (int m = 0; m < 4; ++m)
        #pragma unroll
        for (int r = 0; r < 4; ++r) p4[m][r] = 0.0f;

    #pragma unroll
    for (int t = 0; t < 4; ++t) {
        #pragma unroll
        for (int m = 0; m < 4; ++m) {
            floatx4 acc = {b1v[t], b1v[t], b1v[t], b1v[t]};
            acc = __builtin_amdgcn_mfma_f32_16x16x32_f16(a1[m][0], b1f[0][t], acc, 0, 0, 0);
            acc = __builtin_amdgcn_mfma_f32_16x16x32_f16(a1[m][1], b1f[1][t], acc, 0, 0, 0);
            #pragma unroll
            for (int r = 0; r < 4; ++r)
                p4[m][r] = fmaf(fmaxf(acc[r], 0.0f), w2v[t], p4[m][r]);
        }
    }

    // reduce partials across the 16 cols (lanes differing in low 4 bits)
    #pragma unroll
    for (int m = 0; m < 4; ++m)
        #pragma unroll
        for (int r = 0; r < 4; ++r) {
            float v = p4[m][r];
            v += __shfl_xor(v, 1, 64);
            v += __shfl_xor(v, 2, 64);
            v += __shfl_xor(v, 4, 64);
            v += __shfl_xor(v, 8, 64);
            p4[m][r] = v + b2s;
        }

    // lane c==0 of each quad publishes its 16 point results into the arena
    // (h0 region is dead after the A1 reads; MFMA data-deps drained them)
    float* yf = (float*)wa;
    if (c == 0) {
        #pragma unroll
        for (int m = 0; m < 4; ++m)
            #pragma unroll
            for (int r = 0; r < 4; ++r)
                yf[m * 16 + q * 4 + r] = p4[m][r];
    }
    __syncthreads();   // fence: yf writes -> yf reads
    out[orig] = yf[lane];
}

// ---- fallback (unsorted, original layout, pure fp32) used if ws too small ----
__global__ __launch_bounds__(256, 3) void amgsrn_fused_fallback(
    const float* __restrict__ xs,
    const float* __restrict__ rot,
    const float* __restrict__ scl,
    const float* __restrict__ trn,
    const float* __restrict__ grids,
    const float* __restrict__ W0,
    const float* __restrict__ b0,
    const float* __restrict__ W1,
    const float* __restrict__ b1,
    const float* __restrict__ W2,
    const float* __restrict__ b2,
    float* __restrict__ out)
{
    __shared__ float sM[NG][12];
    const int tid = threadIdx.x;
    if (tid < NG) {
        const int g = tid;
        float qx = rot[g*4+0], qy = rot[g*4+1], qz = rot[g*4+2], qw = rot[g*4+3];
        const float inv = 1.0f / sqrtf(qx*qx + qy*qy + qz*qz + qw*qw);
        qx *= inv; qy *= inv; qz *= inv; qw *= inv;
        const float sx = expf(scl[g*3+0]);
        const float sy = expf(scl[g*3+1]);
        const float sz = expf(scl[g*3+2]);
        sM[g][0] = sx * (1.0f - 2.0f*(qy*qy + qz*qz));
        sM[g][1] = sx * (2.0f*(qx*qy - qz*qw));
        sM[g][2] = sx * (2.0f*(qx*qz + qy*qw));
        sM[g][3] = sy * (2.0f*(qx*qy + qz*qw));
        sM[g][4] = sy * (1.0f - 2.0f*(qx*qx + qz*qz));
        sM[g][5] = sy * (2.0f*(qy*qz - qx*qw));
        sM[g][6] = sz * (2.0f*(qx*qz - qy*qw));
        sM[g][7] = sz * (2.0f*(qy*qz + qx*qw));
        sM[g][8] = sz * (1.0f - 2.0f*(qx*qx + qy*qy));
        sM[g][9]  = trn[g*3+0];
        sM[g][10] = trn[g*3+1];
        sM[g][11] = trn[g*3+2];
    }
    __syncthreads();

    const int n = blockIdx.x * blockDim.x + tid;
    if (n >= NPTS) return;
    const float px = xs[n*3+0];
    const float py = xs[n*3+1];
    const float pz = xs[n*3+2];

    float h0[NNODES];
    #pragma unroll
    for (int j = 0; j < NNODES; ++j) h0[j] = b0[j];

    #pragma unroll
    for (int g = 0; g < NG; ++g) {
        const float* m = sM[g];
        const float tx = m[0]*px + m[1]*py + m[2]*pz + m[9];
        const float ty = m[3]*px + m[4]*py + m[5]*pz + m[10];
        const float tz = m[6]*px + m[7]*py + m[8]*pz + m[11];
        const float fx = (tx + 1.0f) * 31.5f;
        const float fy = (ty + 1.0f) * 31.5f;
        const float fz = (tz + 1.0f) * 31.5f;
        const float x0f = floorf(fx), y0f = floorf(fy), z0f = floorf(fz);
        const float wx = fx - x0f, wy = fy - y0f, wz = fz - z0f;
        const int x0 = (int)x0f, y0 = (int)y0f, z0 = (int)z0f;
        const float* gb = grids + (size_t)g * (size_t)(2 * GR3);
        float f0 = 0.0f, f1 = 0.0f;
        #pragma unroll
        for (int dz = 0; dz < 2; ++dz) {
            #pragma unroll
            for (int dy = 0; dy < 2; ++dy) {
                #pragma unroll
                for (int dx = 0; dx < 2; ++dx) {
                    const int xi = x0 + dx, yi = y0 + dy, zi = z0 + dz;
                    const bool valid = ((unsigned)xi < (unsigned)GR) &
                                       ((unsigned)yi < (unsigned)GR) &
                                       ((unsigned)zi < (unsigned)GR);
                    const int xc = min(max(xi, 0), GR-1);
                    const int yc = min(max(yi, 0), GR-1);
                    const int zc = min(max(zi, 0), GR-1);
                    float w = (dx ? wx : 1.0f - wx) *
                              (dy ? wy : 1.0f - wy) *
                              (dz ? wz : 1.0f - wz);
                    w = valid ? w : 0.0f;
                    const int idx = (zc * GR + yc) * GR + xc;
                    f0 = fmaf(w, gb[idx], f0);
                    f1 = fmaf(w, gb[idx + GR3], f1);
                }
            }
        }
        const float* w0a = W0 + (2*g    ) * NNODES;
        const float* w0b = W0 + (2*g + 1) * NNODES;
        #pragma unroll
        for (int j = 0; j < NNODES; ++j)
            h0[j] = fmaf(f1, w0b[j], fmaf(f0, w0a[j], h0[j]));
    }
    #pragma unroll
    for (int j = 0; j < NNODES; ++j) h0[j] = fmaxf(h0[j], 0.0f);

    float y = b2[0];
    #pragma unroll
    for (int half = 0; half < 2; ++half) {
        float h1[32];
        #pragma unroll
        for (int j = 0; j < 32; ++j) h1[j] = b1[half * 32 + j];
        #pragma unroll
        for (int k = 0; k < NNODES; ++k) {
            const float a = h0[k];
            const float* w = W1 + k * NNODES + half * 32;
            #pragma unroll
            for (int j = 0; j < 32; ++j) h1[j] = fmaf(a, w[j], h1[j]);
        }
        #pragma unroll
        for (int j = 0; j < 32; ++j) y = fmaf(fmaxf(h1[j], 0.0f), W2[half * 32 + j], y);
    }

    out[n] = y;
}

extern "C" void kernel_launch(void* const* d_in, const int* in_sizes, int n_in,
                              void* d_out, int out_size, void* d_ws, size_t ws_size,
                              hipStream_t stream) {
    const float* xs  = (const float*)d_in[0];
    const float* rot = (const float*)d_in[1];
    const float* scl = (const float*)d_in[2];
    const float* trn = (const float*)d_in[3];
    const float* gr  = (const float*)d_in[4];
    const float* W0  = (const float*)d_in[5];
    const float* b0  = (const float*)d_in[6];
    const float* W1  = (const float*)d_in[7];
    const float* b1  = (const float*)d_in[8];
    const float* W2  = (const float*)d_in[9];
    const float* b2  = (const float*)d_in[10];
    float* out = (float*)d_out;

    if (ws_size < WS_TOTAL) {
        dim3 grid((NPTS + 255) / 256), block(256);
        hipLaunchKernelGGL(amgsrn_fused_fallback, grid, block, 0, stream,
                           xs, rot, scl, trn, gr, W0, b0, W1, b1, W2, b2, out);
        return;
    }

    char* ws = (char*)d_ws;
    uint2*    gridsP  = (uint2*)(ws);
    float4*   sorted  = (float4*)(ws + WS_SORT);
    unsigned* keyrank = (unsigned*)(ws + WS_KEYR);
    unsigned* bins    = (unsigned*)(ws + WS_BINS);
    float*    mats    = (float*)(ws + WS_MATS);
    uint4*    wpack   = (uint4*)(ws + WS_WPACK);
    unsigned* part    = (unsigned*)(ws + WS_PART);

    (void)hipMemsetAsync(bins, 0, BINS_BYTES, stream);
    hipLaunchKernelGGL(prep_kernel, dim3(PREP_REPACK + PREP_HIST + 2), dim3(256), 0, stream,
                       gr, gridsP, xs, bins, keyrank,
                       rot, scl, trn, mats, W0, W1, wpack);
    hipLaunchKernelGGL(scanA_kernel, dim3(NBINS / 256), dim3(256), 0, stream, bins, part);
    hipLaunchKernelGGL(scatter_kernel, dim3(NPTS / 256), dim3(256), 0, stream,
                       xs, bins, part, keyrank, sorted);
    hipLaunchKernelGGL(amgsrn_main, dim3(NPTS / 256), dim3(256), 0, stream,
                       sorted, gridsP, mats, wpack, b0, b1, W2, b2, out);
}